// Round 5
// baseline (370.985 us; speedup 1.0000x reference)
//
#include <hip/hip_runtime.h>
#include <math.h>

// Problem constants: x [16,64,256,256] f32, mask [16,256,256] i32
#define BATCH 16
#define CH    64
#define HW    65536          // 256*256
#define HW4   16384          // HW/4 (float4 units)
#define NBLKA 1024           // pool kernel: 64 blocks/batch * 16 batches

#define RED4(t)                                                   \
    vmax.x = fmaxf(vmax.x, (t).x); vmax.y = fmaxf(vmax.y, (t).y); \
    vmax.z = fmaxf(vmax.z, (t).z); vmax.w = fmaxf(vmax.w, (t).w); \
    vmin.x = fminf(vmin.x, (t).x); vmin.y = fminf(vmin.y, (t).y); \
    vmin.z = fminf(vmin.z, (t).z); vmin.w = fminf(vmin.w, (t).w); \
    vsum.x += (t).x; vsum.y += (t).y; vsum.z += (t).z; vsum.w += (t).w;

// ws: per-block partials, 8 floats each: cnt, S1[3], S2[3], pad.
// Contention-free slots -> no init needed (every slot written before read).

__global__ __launch_bounds__(256) void pool_stats_kernel(
    const float* __restrict__ x, const int* __restrict__ mask,
    float* __restrict__ out, float* __restrict__ part)
{
    const int b    = blockIdx.x >> 6;          // batch
    const int pblk = blockIdx.x & 63;          // pixel-block within batch
    const int idx4 = pblk * 256 + threadIdx.x; // float4 index in [0, HW4)

    const float4* xb = (const float4*)x + (size_t)b * CH * HW4 + idx4;

    // Channel-order rotation: without it, all blocks visit channel c in
    // lockstep and (at ~4KB HBM interleave) the grid hits only half the HBM
    // channels at any instant. Rotating by (pblk+b) spreads simultaneous
    // accesses across all 64 channel positions.
    const int rot = (pblk + b) & 63;

    float4 vmax = make_float4(-INFINITY, -INFINITY, -INFINITY, -INFINITY);
    float4 vmin = make_float4( INFINITY,  INFINITY,  INFINITY,  INFINITY);
    float4 vsum = make_float4(0.f, 0.f, 0.f, 0.f);

    for (int i = 0; i < CH; i += 8) {
        float4 t[8];
#pragma unroll
        for (int j = 0; j < 8; ++j) {
            int c = i + j + rot;
            c = (c >= CH) ? c - CH : c;
            t[j] = xb[(size_t)c * HW4];
        }
#pragma unroll
        for (int j = 0; j < 8; ++j) { RED4(t[j]); }
    }

    const float inv = 1.0f / 64.0f;
    float4 vmean = make_float4(vsum.x * inv, vsum.y * inv, vsum.z * inv, vsum.w * inv);

    // write pooled channels [max, mean, min] into d_out [B,3,H,W]
    float4* ob = (float4*)out + (size_t)b * 3 * HW4 + idx4;
    ob[0]       = vmax;
    ob[HW4]     = vmean;
    ob[2 * HW4] = vmin;

    // masked partial sums for this thread's 4 pixels
    int4 mk = ((const int4*)mask)[(size_t)b * HW4 + idx4];
    float vals[7] = {0.f, 0.f, 0.f, 0.f, 0.f, 0.f, 0.f}; // cnt, S1[3], S2[3]
    if (mk.x == 1) { vals[0] += 1.f;
        vals[1] += vmax.x;  vals[4] += vmax.x  * vmax.x;
        vals[2] += vmean.x; vals[5] += vmean.x * vmean.x;
        vals[3] += vmin.x;  vals[6] += vmin.x  * vmin.x; }
    if (mk.y == 1) { vals[0] += 1.f;
        vals[1] += vmax.y;  vals[4] += vmax.y  * vmax.y;
        vals[2] += vmean.y; vals[5] += vmean.y * vmean.y;
        vals[3] += vmin.y;  vals[6] += vmin.y  * vmin.y; }
    if (mk.z == 1) { vals[0] += 1.f;
        vals[1] += vmax.z;  vals[4] += vmax.z  * vmax.z;
        vals[2] += vmean.z; vals[5] += vmean.z * vmean.z;
        vals[3] += vmin.z;  vals[6] += vmin.z  * vmin.z; }
    if (mk.w == 1) { vals[0] += 1.f;
        vals[1] += vmax.w;  vals[4] += vmax.w  * vmax.w;
        vals[2] += vmean.w; vals[5] += vmean.w * vmean.w;
        vals[3] += vmin.w;  vals[6] += vmin.w  * vmin.w; }

    // wave (64-lane) shuffle reduction
    for (int off = 32; off > 0; off >>= 1) {
#pragma unroll
        for (int k = 0; k < 7; ++k)
            vals[k] += __shfl_down(vals[k], off, 64);
    }

    // cross-wave (4 waves) LDS reduction -> one contention-free slot per block
    __shared__ float red[4][8];
    const int lane = threadIdx.x & 63;
    const int wid  = threadIdx.x >> 6;
    if (lane == 0) {
#pragma unroll
        for (int k = 0; k < 7; ++k) red[wid][k] = vals[k];
    }
    __syncthreads();
    if (threadIdx.x < 7) {
        const int k = threadIdx.x;
        part[blockIdx.x * 8 + k] = red[0][k] + red[1][k] + red[2][k] + red[3][k];
    }
}

// One block per 256 float4s of out; folds stats finalization (redundant
// per-block reduce of 64 partial slots, ~2 KB from L2) + masked normalize.
__global__ __launch_bounds__(256) void norm_kernel(
    float* __restrict__ out, const int* __restrict__ mask,
    const float* __restrict__ part)
{
    const int i4   = blockIdx.x * 256 + threadIdx.x;   // [0, 3*B*HW4)
    const int bc   = i4 >> 14;                         // (b*3 + c)
    const int idx4 = i4 & (HW4 - 1);
    const int b    = bc / 3;

    // redundant stats reduce: batch b's 64 partial slots
    __shared__ float sstat[6];   // mean[3], rstd[3]
    if (threadIdx.x < 64) {
        const float* pb = part + (size_t)(b * 64 + threadIdx.x) * 8;
        float s[7];
#pragma unroll
        for (int k = 0; k < 7; ++k) s[k] = pb[k];
        for (int off = 32; off > 0; off >>= 1) {
#pragma unroll
            for (int k = 0; k < 7; ++k)
                s[k] += __shfl_down(s[k], off, 64);
        }
        if (threadIdx.x == 0) {
            const float cnt = s[0];
#pragma unroll
            for (int c = 0; c < 3; ++c) {
                const float S1 = s[1 + c];
                const float S2 = s[4 + c];
                sstat[c]     = S1 / cnt;
                sstat[3 + c] = 1.0f / sqrtf((S2 - S1 * S1 / cnt) / (cnt - 1.0f));
            }
        }
    }
    __syncthreads();

    const int   c    = bc - b * 3;
    const float mean = sstat[c];
    const float rstd = sstat[3 + c];

    float4 v = ((const float4*)out)[i4];
    int4 mk  = ((const int4*)mask)[(size_t)b * HW4 + idx4];
    v.x = (mk.x == 1) ? (v.x - mean) * rstd : 0.0f;
    v.y = (mk.y == 1) ? (v.y - mean) * rstd : 0.0f;
    v.z = (mk.z == 1) ? (v.z - mean) * rstd : 0.0f;
    v.w = (mk.w == 1) ? (v.w - mean) * rstd : 0.0f;
    ((float4*)out)[i4] = v;
}

extern "C" void kernel_launch(void* const* d_in, const int* in_sizes, int n_in,
                              void* d_out, int out_size, void* d_ws, size_t ws_size,
                              hipStream_t stream)
{
    const float* x    = (const float*)d_in[0];
    const int*   mask = (const int*)d_in[1];
    float*       out  = (float*)d_out;
    float*       part = (float*)d_ws;

    pool_stats_kernel<<<NBLKA, 256, 0, stream>>>(x, mask, out, part);
    norm_kernel<<<3 * BATCH * HW4 / 256, 256, 0, stream>>>(out, mask, part);
}

// Round 6
// 368.280 us; speedup vs baseline: 1.0073x; 1.0073x over previous
//
#include <hip/hip_runtime.h>
#include <math.h>

// Problem constants: x [16,64,256,256] f32, mask [16,256,256] i32
#define BATCH 16
#define CH    64
#define HW    65536          // 256*256
#define HW4   16384          // HW/4 (float4 units)
#define NBLKA 2048           // pool: 128 blocks/batch * 16 batches (128-thr blocks)

#define RED4(t)                                                   \
    vmax.x = fmaxf(vmax.x, (t).x); vmax.y = fmaxf(vmax.y, (t).y); \
    vmax.z = fmaxf(vmax.z, (t).z); vmax.w = fmaxf(vmax.w, (t).w); \
    vmin.x = fminf(vmin.x, (t).x); vmin.y = fminf(vmin.y, (t).y); \
    vmin.z = fminf(vmin.z, (t).z); vmin.w = fminf(vmin.w, (t).w); \
    vsum.x += (t).x; vsum.y += (t).y; vsum.z += (t).z; vsum.w += (t).w;

// ws: per-block partials, 8 floats each: cnt, S1[3], S2[3], pad.
// Contention-free slots -> no init needed (every slot written before read).

// 128-thread blocks: 16 blocks/CU (HW max) x 128 = 2048 threads = 32 waves/CU
// (full wave residency; the 256-thr/1024-block shape parked at 16 waves/CU).
// __launch_bounds__(128,8): 8 waves/EU -> VGPR capped at 64 so residency holds.
__global__ __launch_bounds__(128, 8) void pool_stats_kernel(
    const float* __restrict__ x, const int* __restrict__ mask,
    float* __restrict__ out, float* __restrict__ part)
{
    const int b    = blockIdx.x >> 7;           // batch
    const int pblk = blockIdx.x & 127;          // pixel-block within batch
    const int idx4 = pblk * 128 + threadIdx.x;  // float4 index in [0, HW4)

    const float4* xb = (const float4*)x + (size_t)b * CH * HW4 + idx4;

    float4 vmax = make_float4(-INFINITY, -INFINITY, -INFINITY, -INFINITY);
    float4 vmin = make_float4( INFINITY,  INFINITY,  INFINITY,  INFINITY);
    float4 vsum = make_float4(0.f, 0.f, 0.f, 0.f);

    for (int c0 = 0; c0 < CH; c0 += 4) {
        float4 t[4];
#pragma unroll
        for (int j = 0; j < 4; ++j)
            t[j] = xb[(size_t)(c0 + j) * HW4];
#pragma unroll
        for (int j = 0; j < 4; ++j) { RED4(t[j]); }
    }

    const float inv = 1.0f / 64.0f;
    float4 vmean = make_float4(vsum.x * inv, vsum.y * inv, vsum.z * inv, vsum.w * inv);

    // write pooled channels [max, mean, min] into d_out [B,3,H,W]
    float4* ob = (float4*)out + (size_t)b * 3 * HW4 + idx4;
    ob[0]       = vmax;
    ob[HW4]     = vmean;
    ob[2 * HW4] = vmin;

    // masked partial sums for this thread's 4 pixels
    int4 mk = ((const int4*)mask)[(size_t)b * HW4 + idx4];
    float vals[7] = {0.f, 0.f, 0.f, 0.f, 0.f, 0.f, 0.f}; // cnt, S1[3], S2[3]
    if (mk.x == 1) { vals[0] += 1.f;
        vals[1] += vmax.x;  vals[4] += vmax.x  * vmax.x;
        vals[2] += vmean.x; vals[5] += vmean.x * vmean.x;
        vals[3] += vmin.x;  vals[6] += vmin.x  * vmin.x; }
    if (mk.y == 1) { vals[0] += 1.f;
        vals[1] += vmax.y;  vals[4] += vmax.y  * vmax.y;
        vals[2] += vmean.y; vals[5] += vmean.y * vmean.y;
        vals[3] += vmin.y;  vals[6] += vmin.y  * vmin.y; }
    if (mk.z == 1) { vals[0] += 1.f;
        vals[1] += vmax.z;  vals[4] += vmax.z  * vmax.z;
        vals[2] += vmean.z; vals[5] += vmean.z * vmean.z;
        vals[3] += vmin.z;  vals[6] += vmin.z  * vmin.z; }
    if (mk.w == 1) { vals[0] += 1.f;
        vals[1] += vmax.w;  vals[4] += vmax.w  * vmax.w;
        vals[2] += vmean.w; vals[5] += vmean.w * vmean.w;
        vals[3] += vmin.w;  vals[6] += vmin.w  * vmin.w; }

    // wave (64-lane) shuffle reduction
    for (int off = 32; off > 0; off >>= 1) {
#pragma unroll
        for (int k = 0; k < 7; ++k)
            vals[k] += __shfl_down(vals[k], off, 64);
    }

    // cross-wave (2 waves) LDS reduction -> one contention-free slot per block
    __shared__ float red[2][8];
    const int lane = threadIdx.x & 63;
    const int wid  = threadIdx.x >> 6;
    if (lane == 0) {
#pragma unroll
        for (int k = 0; k < 7; ++k) red[wid][k] = vals[k];
    }
    __syncthreads();
    if (threadIdx.x < 7) {
        const int k = threadIdx.x;
        part[blockIdx.x * 8 + k] = red[0][k] + red[1][k];
    }
}

// One block per 256 float4s of out; folds stats finalization (redundant
// per-block reduce of 128 partial slots, ~4 KB from L2) + masked normalize.
__global__ __launch_bounds__(256) void norm_kernel(
    float* __restrict__ out, const int* __restrict__ mask,
    const float* __restrict__ part)
{
    const int i4   = blockIdx.x * 256 + threadIdx.x;   // [0, 3*B*HW4)
    const int bc   = i4 >> 14;                         // (b*3 + c)
    const int idx4 = i4 & (HW4 - 1);
    const int b    = bc / 3;

    // redundant stats reduce: batch b's 128 partial slots (2 per lane)
    __shared__ float sstat[6];   // mean[3], rstd[3]
    if (threadIdx.x < 64) {
        const float* pb = part + (size_t)(b * 128 + threadIdx.x * 2) * 8;
        float s[7];
#pragma unroll
        for (int k = 0; k < 7; ++k) s[k] = pb[k] + pb[8 + k];
        for (int off = 32; off > 0; off >>= 1) {
#pragma unroll
            for (int k = 0; k < 7; ++k)
                s[k] += __shfl_down(s[k], off, 64);
        }
        if (threadIdx.x == 0) {
            const float cnt = s[0];
#pragma unroll
            for (int c = 0; c < 3; ++c) {
                const float S1 = s[1 + c];
                const float S2 = s[4 + c];
                sstat[c]     = S1 / cnt;
                sstat[3 + c] = 1.0f / sqrtf((S2 - S1 * S1 / cnt) / (cnt - 1.0f));
            }
        }
    }
    __syncthreads();

    const int   c    = bc - b * 3;
    const float mean = sstat[c];
    const float rstd = sstat[3 + c];

    float4 v = ((const float4*)out)[i4];
    int4 mk  = ((const int4*)mask)[(size_t)b * HW4 + idx4];
    v.x = (mk.x == 1) ? (v.x - mean) * rstd : 0.0f;
    v.y = (mk.y == 1) ? (v.y - mean) * rstd : 0.0f;
    v.z = (mk.z == 1) ? (v.z - mean) * rstd : 0.0f;
    v.w = (mk.w == 1) ? (v.w - mean) * rstd : 0.0f;
    ((float4*)out)[i4] = v;
}

extern "C" void kernel_launch(void* const* d_in, const int* in_sizes, int n_in,
                              void* d_out, int out_size, void* d_ws, size_t ws_size,
                              hipStream_t stream)
{
    const float* x    = (const float*)d_in[0];
    const int*   mask = (const int*)d_in[1];
    float*       out  = (float*)d_out;
    float*       part = (float*)d_ws;

    pool_stats_kernel<<<NBLKA, 128, 0, stream>>>(x, mask, out, part);
    norm_kernel<<<3 * BATCH * HW4 / 256, 256, 0, stream>>>(out, mask, part);
}